// Round 8
// baseline (278.956 us; speedup 1.0000x reference)
//
#include <hip/hip_runtime.h>

// ---------------------------------------------------------------------------
// DualAttention on MI355X.  B=8 L=8 C=64 W=32 (WH=1024, LWH=8192) NH=128 FS=5
// R8: 5-kernel pipeline.
//  - spat QK computes S^T (swap MFMA args) -> P written as 16 ds_write_b64
//    per wave-iter instead of 64 ds_write_u16.  P [qrow][kv] stride 68.
//  - chan softmax fused into chan_B (re-reduce S partials from L2, exp->LDS
//    P tile, 1/sum folded into PV epilogue row scale) -> one fewer stage.
//  - K4 = both conv5 stems (512 blocks); K5 = both finals (512 blocks).
// ---------------------------------------------------------------------------

#define LOG2E 1.44269504088896340736f

typedef __attribute__((ext_vector_type(8))) short short8;   // bf16 x8 frag
typedef __attribute__((ext_vector_type(4))) float f4;       // fp32 x4 frag

#define MFMA16(a, b, c) __builtin_amdgcn_mfma_f32_16x16x32_bf16(a, b, c, 0, 0, 0)

#define GLOAD_LDS16(gp, lp) __builtin_amdgcn_global_load_lds( \
    (const __attribute__((address_space(1))) void*)(gp), \
    (__attribute__((address_space(3))) void*)(lp), 16, 0, 0)

__device__ __forceinline__ unsigned short f2bf(float f) {   // RNE float->bf16
  union { float f; unsigned u; } v; v.f = f;
  unsigned r = v.u + 0x7FFFu + ((v.u >> 16) & 1u);
  return (unsigned short)(r >> 16);
}
__device__ __forceinline__ float bf2f(unsigned short h) {
  union { unsigned u; float f; } v; v.u = ((unsigned)h) << 16;
  return v.f;
}
__device__ __forceinline__ unsigned pack2_rz(float a, float b) { // [b|a] bf16x2
  union { float f; unsigned u; } x, y; x.f = a; y.f = b;
  return (x.u >> 16) | (y.u & 0xFFFF0000u);
}
__device__ __forceinline__ unsigned pack2_rne(float a, float b) {
  return (unsigned)f2bf(a) | ((unsigned)f2bf(b) << 16);
}
__device__ __forceinline__ float exp2fast(float x) {
#if __has_builtin(__builtin_amdgcn_exp2f)
  return __builtin_amdgcn_exp2f(x);
#else
  return exp2f(x);
#endif
}

// ---------------- workspace layout (bytes), total ~45.0MB ------------------
#define O_STATS 0ul                      // [2][8][2] f32 (memset 0)
#define O_W1T   256ul                    // [2][25][64][64] bf16
#define O_W2B   409856ul                 // [2][128][64] bf16
#define O_LNW   442624ul                 // [2][1024][64] bf16 (transposed lnw)
#define O_LNB   704768ul                 // [2][1024][64] bf16
#define O_QT    966912ul                 // [8][1024][64] bf16  q^T
#define O_KSP   2015488ul                // [8][8192][64] bf16  spatial K *LOG2E
#define O_VT    10404096ul               // [8][64][8192] bf16  spatial V^T
#define O_NUM   18792704ul               // [8][1024][16][64] bf16 spat num part
#define O_DEN   35569920ul               // [8][1024][16] f32      spat den part
#define O_SP    36094208ul               // [4][8][64][512] f32 chan S partials
#define O_XS    40812800ul               // [8][1024][64] bf16 stem in (spatial)
#define O_XC    41861376ul               // [8][1024][64] bf16 stem in (channel)
#define O_YT    42909952ul               // [2][8][1024][64] bf16 conv1 out

// ============================================================================
// K1: tile transposes + LN transposes + weights.  grid 3104.
// ============================================================================
__global__ __launch_bounds__(256) void k1_prep(
    const float* __restrict__ q, const float* __restrict__ keys,
    const float* __restrict__ values,
    const float* __restrict__ sw1, const float* __restrict__ slnw,
    const float* __restrict__ slnb, const float* __restrict__ sw2,
    const float* __restrict__ cw1, const float* __restrict__ clnw,
    const float* __restrict__ clnb, const float* __restrict__ cw2,
    char* __restrict__ ws)
{
  __shared__ float T[64][65];
  const int job = blockIdx.x, t = threadIdx.x;

  if (job < 2240) {                      // ---- tile jobs ----
    int kind, mat = 0, sel = 0;
    if (job < 1024)      { kind = 0; mat = job >> 4; }
    else if (job < 2048) { kind = 1; mat = (job - 1024) >> 4; }
    else if (job < 2176) { kind = 2; mat = (job - 2048) >> 4; }
    else                 { kind = 3; sel = (job - 2176) >> 4; }
    const int pt = job & 15, p0 = pt * 64;
    const float* src =
        kind == 0 ? keys : kind == 1 ? values : kind == 2 ? q
        : (sel == 0 ? slnw : sel == 1 ? slnb : sel == 2 ? clnw : clnb);
    src += (size_t)mat * 65536;

    const int r0 = t >> 4, c4 = (t & 15) * 4;
    if (kind == 1) {                     // identity only: V^T[b][c][l*1024+p]
      unsigned short* VTp = (unsigned short*)(ws + O_VT);
      const int b = mat >> 3, l = mat & 7;
#pragma unroll
      for (int pass = 0; pass < 4; ++pass) {
        const int r = pass * 16 + r0;
        float4 v = *(const float4*)(src + (size_t)r * 1024 + p0 + c4);
        ushort4 o;
        o.x = f2bf(v.x); o.y = f2bf(v.y); o.z = f2bf(v.z); o.w = f2bf(v.w);
        *(ushort4*)(VTp + ((size_t)b * 64 + r) * 8192 + l * 1024 + p0 + c4) = o;
      }
      return;
    }
#pragma unroll
    for (int pass = 0; pass < 4; ++pass) {
      const int r = pass * 16 + r0;
      float4 v = *(const float4*)(src + (size_t)r * 1024 + p0 + c4);
      T[r][c4] = v.x; T[r][c4 + 1] = v.y; T[r][c4 + 2] = v.z; T[r][c4 + 3] = v.w;
    }
    __syncthreads();
#pragma unroll
    for (int pass = 0; pass < 2; ++pass) {
      const int p = pass * 32 + (t >> 3), cs = (t & 7) * 8;
      short8 o;
      if (kind == 0) {                   // Ksp[b][l*1024+p][c] * LOG2E
#pragma unroll
        for (int j = 0; j < 8; ++j) o[j] = (short)f2bf(T[cs + j][p] * LOG2E);
        const int b = mat >> 3, l = mat & 7;
        *(short8*)((unsigned short*)(ws + O_KSP) +
                   ((size_t)b * 8192 + l * 1024 + p0 + p) * 64 + cs) = o;
      } else if (kind == 2) {            // Qt[b][p][c]
#pragma unroll
        for (int j = 0; j < 8; ++j) o[j] = (short)f2bf(T[cs + j][p]);
        *(short8*)((unsigned short*)(ws + O_QT) +
                   ((size_t)mat * 1024 + p0 + p) * 64 + cs) = o;
      } else {                           // LN param^T [s][p][c]
#pragma unroll
        for (int j = 0; j < 8; ++j) o[j] = (short)f2bf(T[cs + j][p]);
        unsigned long off = (sel & 1) ? O_LNB : O_LNW;
        *(short8*)((unsigned short*)(ws + off) +
                   ((size_t)(sel >> 1) * 1024 + p0 + p) * 64 + cs) = o;
      }
    }
    return;
  }

  // ---- weights ----
  {
    unsigned i = (job - 2240) * 256u + t;
    if (i < 204800u) {                   // W1t[s][off][co][ci] <- w1[co][ci][off]
      unsigned ci = i & 63u, co = (i >> 6) & 63u, tt = i >> 12;
      unsigned off = tt % 25u, st = tt / 25u;
      const float* w = st ? cw1 : sw1;
      ((unsigned short*)(ws + O_W1T))[i] = f2bf(w[(co * 64u + ci) * 25u + off]);
      return;
    }
    i -= 204800u;
    if (i < 16384u) {                    // W2b[s][nh][c]
      unsigned c = i & 63u, nh = (i >> 6) & 127u, st = i >> 13;
      const float* w = st ? cw2 : sw2;
      ((unsigned short*)(ws + O_W2B))[i] = f2bf(w[nh * 64u + c]);
    }
  }
}

// ============================================================================
// K2: spat_attn (blocks 0..511) ∪ chan_S (512..639)
// spat LDS map (bytes): Kt dbuf @0 (2x8192), Vt dbuf @16384 (2x8192),
//   P tiles @32768: per wave 64 rows x 68 cols bf16 (8704B).  Total 67584.
// ============================================================================
__global__ __launch_bounds__(256) void k2_spat_chanS(
    const float* __restrict__ q, const float* __restrict__ keys,
    char* __restrict__ ws)
{
  __shared__ __align__(16) unsigned char SM[67584];

  if (blockIdx.x < 512) {                // ================= spatial =========
    unsigned short* KtB = (unsigned short*)SM;             // [2][4096]
    unsigned short* VtB = (unsigned short*)(SM + 16384);   // [2][4096]

    const unsigned short* QT = (const unsigned short*)(ws + O_QT);
    const unsigned short* KSP = (const unsigned short*)(ws + O_KSP);
    const unsigned short* VTg = (const unsigned short*)(ws + O_VT);
    unsigned short* NUM = (unsigned short*)(ws + O_NUM);
    float* DEN = (float*)(ws + O_DEN);

    const int b = blockIdx.x >> 6;
    const int qt = (blockIdx.x >> 4) & 3;
    const int s = blockIdx.x & 15;
    const int t = threadIdx.x;
    const int w = t >> 6, lane = t & 63;
    const int low4 = lane & 15, quad = lane >> 4;

    unsigned short* Pw = (unsigned short*)(SM + 32768) + w * 4352; // 64x68

    const unsigned short* KSPb = KSP + (size_t)b * 8192 * 64;
    const unsigned short* VTb = VTg + (size_t)b * 64 * 8192;
    const int qbase = qt * 256 + w * 64;
    const int kvbase = s * 512;

    int cn[2], cks[2], cqd[2], cl4[2];
#pragma unroll
    for (int pass = 0; pass < 2; ++pass) {
      const int c = pass * 256 + t;
      cn[pass] = c >> 7; cks[pass] = (c >> 6) & 1;
      cqd[pass] = (c >> 4) & 3; cl4[pass] = c & 15;
    }

    short8 qa[4][2];
#pragma unroll
    for (int mi = 0; mi < 4; ++mi)
#pragma unroll
      for (int ks = 0; ks < 2; ++ks)
        qa[mi][ks] = *(const short8*)(QT +
            ((size_t)(b * 1024 + qbase + mi * 16 + low4)) * 64 + ks * 32 + quad * 8);

    short8 vones;
#pragma unroll
    for (int j = 0; j < 8; ++j) vones[j] = (short)0x3F80;

    f4 accO[4][4], accD[4];
#pragma unroll
    for (int m = 0; m < 4; ++m) {
      accD[m] = (f4){0.f, 0.f, 0.f, 0.f};
#pragma unroll
      for (int n = 0; n < 4; ++n) accO[m][n] = (f4){0.f, 0.f, 0.f, 0.f};
    }

#pragma unroll
    for (int pass = 0; pass < 2; ++pass) {
      GLOAD_LDS16(KSPb + ((size_t)(kvbase + cn[pass] * 16 + cl4[pass])) * 64 +
                      cks[pass] * 32 + cqd[pass] * 8,
                  &KtB[(pass * 256 + w * 64) * 8]);
      GLOAD_LDS16(VTb + ((size_t)(cn[pass] * 16 + cl4[pass])) * 8192 + kvbase +
                      cks[pass] * 32 + cqd[pass] * 8,
                  &VtB[(pass * 256 + w * 64) * 8]);
    }

    for (int it = 0; it < 8; ++it) {
      const int d = it & 1;
      __syncthreads();
      if (it < 7) {
        const int kv1 = kvbase + (it + 1) * 64;
        const int dn = (d ^ 1) * 4096;
#pragma unroll
        for (int pass = 0; pass < 2; ++pass) {
          GLOAD_LDS16(KSPb + ((size_t)(kv1 + cn[pass] * 16 + cl4[pass])) * 64 +
                          cks[pass] * 32 + cqd[pass] * 8,
                      &KtB[dn + (pass * 256 + w * 64) * 8]);
          GLOAD_LDS16(VTb + ((size_t)(cn[pass] * 16 + cl4[pass])) * 8192 + kv1 +
                          cks[pass] * 32 + cqd[pass] * 8,
                      &VtB[dn + (pass * 256 + w * 64) * 8]);
        }
      }
      // ---- QK (S^T: A=K, B=Q) + exp2 + packed b64 P writes ----
#pragma unroll
      for (int n = 0; n < 4; ++n) {
        f4 sS[4];
#pragma unroll
        for (int mi = 0; mi < 4; ++mi) sS[mi] = (f4){0.f, 0.f, 0.f, 0.f};
#pragma unroll
        for (int ks = 0; ks < 2; ++ks) {
          short8 kb = *(const short8*)&KtB[d * 4096 + ((n * 2 + ks) * 64 + lane) * 8];
#pragma unroll
          for (int mi = 0; mi < 4; ++mi) sS[mi] = MFMA16(kb, qa[mi][ks], sS[mi]);
        }
        // lane holds: qcol=low4 (within tile mi), kv = n*16 + quad*4 + r
#pragma unroll
        for (int mi = 0; mi < 4; ++mi) {
          float e0 = exp2fast(sS[mi][0]);
          float e1 = exp2fast(sS[mi][1]);
          float e2 = exp2fast(sS[mi][2]);
          float e3 = exp2fast(sS[mi][3]);
          uint2 pk;
          pk.x = pack2_rz(e0, e1);
          pk.y = pack2_rz(e2, e3);
          *(uint2*)&Pw[(mi * 16 + low4) * 68 + n * 16 + quad * 4] = pk;
        }
      }
      // ---- PV + den (MFMA vs ones) ----
#pragma unroll
      for (int ks = 0; ks < 2; ++ks) {
        short8 vb[4];
#pragma unroll
        for (int n2 = 0; n2 < 4; ++n2)
          vb[n2] = *(const short8*)&VtB[d * 4096 + ((n2 * 2 + ks) * 64 + lane) * 8];
#pragma unroll
        for (int m = 0; m < 4; ++m) {
          short8 pa = *(const short8*)&Pw[(m * 16 + low4) * 68 + ks * 32 + quad * 8];
          accD[m] = MFMA16(pa, vones, accD[m]);
#pragma unroll
          for (int n2 = 0; n2 < 4; ++n2) accO[m][n2] = MFMA16(pa, vb[n2], accO[m][n2]);
        }
      }
    }

    // partial stores: NUM bf16, DEN f32 (accD cols all equal = row-sum)
#pragma unroll
    for (int m = 0; m < 4; ++m)
#pragma unroll
      for (int r = 0; r < 4; ++r) {
        const int row = qbase + m * 16 + quad * 4 + r;
        const size_t base = ((size_t)(b * 1024 + row) * 16 + s);
#pragma unroll
        for (int n2 = 0; n2 < 4; ++n2)
          NUM[base * 64 + n2 * 16 + low4] = f2bf(accO[m][n2][r]);
        if (low4 == 0) DEN[base] = accD[m][r];
      }
    return;
  }

  // ================= chan_S =================
  {
    float* Sp = (float*)(ws + O_SP);
    const int bid = blockIdx.x - 512;
    const int b = bid >> 4, colT = (bid >> 2) & 3, kt = bid & 3;
    const int t = threadIdx.x, w = t >> 6, lane = t & 63;
    const int low4 = lane & 15, quad = lane >> 4;
    const int dl = lane >> 1, dh = lane & 1;
    const int k00 = kt * 256;

    f4 acc[4][2];
#pragma unroll
    for (int m = 0; m < 4; ++m)
#pragma unroll
      for (int n = 0; n < 2; ++n) acc[m][n] = (f4){0.f, 0.f, 0.f, 0.f};

    auto stageAll = [&](int bo, int k0) {
#pragma unroll
      for (int gi = 0; gi < 4; ++gi) {           // K: groups w, w+4, w+8, w+12
        const int g = w + gi * 4;
        const int n = g >> 1, sub = g & 1;
        const int l = sub * 32 + dl;
        const float* gp = keys + (size_t)(b * 512 + colT * 128 + n * 16 + (l & 15)) * 1024
                          + k0 + (l >> 4) * 8 + dh * 4;
        GLOAD_LDS16(gp, SM + bo + (size_t)(n * 128 + sub * 64) * 16);
      }
#pragma unroll
      for (int gi = 0; gi < 2; ++gi) {           // Q: groups w, w+4
        const int g = w + gi * 4;
        const int m = g >> 1, sub = g & 1;
        const int l = sub * 32 + dl;
        const float* gp = q + (size_t)(b * 64 + m * 16 + (l & 15)) * 1024
                          + k0 + (l >> 4) * 8 + dh * 4;
        GLOAD_LDS16(gp, SM + bo + 16384 + (size_t)(m * 128 + sub * 64) * 16);
      }
    };

    stageAll(0, k00);
    for (int it = 0; it < 8; ++it) {
      const int bo = (it & 1) * 24576;
      const char* cb = (const char*)SM + bo;
      __syncthreads();
      if (it < 7) stageAll(bo ^ 24576, k00 + (it + 1) * 32);

      short8 ah[4], al[4];
#pragma unroll
      for (int m = 0; m < 4; ++m) {              // A-frags from LDS, *LOG2E, split
        const float* fp = (const float*)(cb + 16384 + (size_t)(m * 128 + lane * 2) * 16);
        float4 u0 = ((const float4*)fp)[0];
        float4 u1 = ((const float4*)fp)[1];
        float vv[8] = {u0.x, u0.y, u0.z, u0.w, u1.x, u1.y, u1.z, u1.w};
#pragma unroll
        for (int j = 0; j < 8; ++j) {
          float sv = vv[j] * LOG2E;
          unsigned short hi = f2bf(sv);
          ah[m][j] = (short)hi;
          al[m][j] = (short)f2bf(sv - bf2f(hi));
        }
      }
#pragma unroll
      for (int n2 = 0; n2 < 2; ++n2) {           // B-frags (this wave's 2 n-tiles)
        const int n = w * 2 + n2;
        const float* fp = (const float*)(cb + (size_t)(n * 128 + lane * 2) * 16);
        float4 u0 = ((const float4*)fp)[0];
        float4 u1 = ((const float4*)fp)[1];
        float vv[8] = {u0.x, u0.y, u0.z, u0.w, u1.x, u1.y, u1.z, u1.w};
        short8 bh, bl;
#pragma unroll
        for (int j = 0; j < 8; ++j) {
          unsigned short hi = f2bf(vv[j]);
          bh[j] = (short)hi;
          bl[j] = (short)f2bf(vv[j] - bf2f(hi));
        }
#pragma unroll
        for (int m = 0; m < 4; ++m) {
          acc[m][n2] = MFMA16(ah[m], bh, acc[m][n2]);
          acc[m][n2] = MFMA16(al[m], bh, acc[m][n2]);
          acc[m][n2] = MFMA16(ah[m], bl, acc[m][n2]);
        }
      }
    }

#pragma unroll
    for (int m = 0; m < 4; ++m)
#pragma unroll
      for (int n2 = 0; n2 < 2; ++n2)
#pragma unroll
        for (int r = 0; r < 4; ++r) {
          const int row = m * 16 + quad * 4 + r;
          const int col = colT * 128 + (w * 2 + n2) * 16 + low4;
          Sp[(((size_t)kt * 8 + b) * 64 + row) * 512 + col] = acc[m][n2][r];
        }
  }
}

// ============================================================================
// K3: spat_fin (0..511) ∪ chan_B+softmax (512..639)
// chanB+soft: per block (b, pt:16 of 64px): re-reduce S partials from L2,
//   row-max, exp2 -> LDS P tile [64][524] bf16, 1/sum -> RS; PV from LDS with
//   row-scale epilogue + residual.
// ============================================================================
__global__ __launch_bounds__(256) void k3_finS_chanB(
    const float* __restrict__ values, char* __restrict__ ws)
{
  __shared__ __align__(16) unsigned short Pl[64 * 524];   // 67072B
  __shared__ float RS[64];
  const unsigned short* QT = (const unsigned short*)(ws + O_QT);

  if (blockIdx.x < 512) {                // ---- spat_fin: 16 bf16 partials ----
    const unsigned short* NUM = (const unsigned short*)(ws + O_NUM);
    const float* DEN = (const float*)(ws + O_DEN);
    unsigned short* Xs = (unsigned short*)(ws + O_XS);

    const unsigned i = blockIdx.x * 256u + threadIdx.x;   // 131072
    const int c0 = (i & 15) * 4;
    const unsigned row = i >> 4;                          // [0, 8192)

    float dtot = 0.f;
#pragma unroll
    for (int sq = 0; sq < 4; ++sq) {
      float4 dv = *(const float4*)(DEN + (size_t)row * 16 + sq * 4);
      dtot += dv.x + dv.y + dv.z + dv.w;
    }
    float n4[4] = {0.f, 0.f, 0.f, 0.f};
#pragma unroll
    for (int s = 0; s < 16; ++s) {
      ushort4 pv = *(const ushort4*)(NUM + ((size_t)row * 16 + s) * 64 + c0);
      n4[0] += bf2f(pv.x); n4[1] += bf2f(pv.y);
      n4[2] += bf2f(pv.z); n4[3] += bf2f(pv.w);
    }
    const float rd = 1.0f / dtot;
    size_t ob = (size_t)row * 64 + c0;
    ushort4 qv = *(const ushort4*)(QT + ob);
    ushort4 o4;
    o4.x = f2bf(n4[0] * rd + bf2f(qv.x));
    o4.y = f2bf(n4[1] * rd + bf2f(qv.y));
    o4.z = f2bf(n4[2] * rd + bf2f(qv.z));
    o4.w = f2bf(n4[3] * rd + bf2f(qv.w));
    *(ushort4*)(Xs + ob) = o4;
    return;
  }

  // ---- chan_B + softmax ----
  {
    const float* Sp = (const float*)(ws + O_SP);
    unsigned short* Xc = (unsigned short*)(ws + O_XC);

    const int bid = blockIdx.x - 512;
    const int b = bid >> 4, pt = bid & 15;
    const int t = threadIdx.x;

    // phase 1+2: softmax over summed partials (4 threads per row)
    const int row = t >> 2, sub = t & 3;
    const float* sp0 = Sp + ((size_t)b * 64 + row) * 512;
    float mx = -1e30f;
#pragma unroll
    for (int i = 0; i < 32; ++i) {
      const int col = i * 16 + sub * 4;
      float4 v0 = *(const float4*)(sp0 + col);
      float4 v1 = *(const float4*)(sp0 + 262144 + col);
      float4 v2 = *(const float4*)(sp0 + 524288 + col);
      float4 v3 = *(const float4*)(sp0 + 786432 + col);
      float s0 = v0.x + v1.x + v2.x + v3.x;
      float s1 = v0.y + v1.y + v2.y + v3.y;
      float s2 = v0.z + v1.z + v2.z + v3.z;
      float s3 = v0.w + v1.w + v2.w + v3.w;
      mx = fmaxf(mx, fmaxf(fmaxf(s0, s1), fmaxf(s2, s3)));
    }
    mx = fmaxf(mx, __shfl_xor(mx, 1, 64));
    mx = fmaxf(mx, __shfl_xor(mx, 2, 64));
    float sum = 0.f;
#pragma unroll
    for (int i = 0; i < 32; ++i) {
      const int col = i * 16 + sub * 4;
      float4 v0 = *(const float4*)(sp0 + col);
      float4 v1 = *(const float4*)(sp0 + 262144 + col);
      float4 v2 = *(const float4*)(sp0 + 524288 + col);
      float4 v3 = *(const float4*)(sp0 + 786432 + col);
      float e0 = exp2fast(v0.x + v1.x + v2.x + v3.x - mx);
      float e1 = exp2fast(v0.y + v1.y + v2.y + v3.y - mx);
      float e2 = exp2fast(v0.z + v1.z + v2.z + v3.z - mx);
      float e3 = exp2fast(v0.w + v1.w + v2.w + v3.w - mx);
      sum += (e0 + e1) + (e2 + e3);
      uint2 pk;
      pk.x = pack2_rne(e0, e1);
      pk.y = pack2_rne(e2, e3);
      *(uint2*)&Pl[row * 524 + col] = pk;
    }
    sum += __shfl_xor(sum, 1, 64);
    sum += __shfl_xor(sum, 2, 64);
    if (sub == 0) RS[row] = 1.0f / sum;
    __syncthreads();

    // phase 3: PV (A from LDS) + row-scale + residual
    const int w = t >> 6, lane = t & 63;
    const int low4 = lane & 15, quad = lane >> 4;
    const int p = pt * 64 + w * 16 + low4;

    f4 acc[4];
#pragma unroll
    for (int m = 0; m < 4; ++m) acc[m] = (f4){0.f, 0.f, 0.f, 0.f};

    const float* vbase = values + (size_t)b * 524288 + p;
    for (int ks = 0; ks < 16; ++ks) {
      short8 vbv;
      const float* vp = vbase + (size_t)(ks * 32 + quad * 8) * 1024;
#pragma unroll
      for (int j = 0; j < 8; ++j) vbv[j] = (short)f2bf(vp[(size_t)j * 1024]);
#pragma unroll
      for (int m = 0; m < 4; ++m) {
        short8 a = *(const short8*)&Pl[(m * 16 + low4) * 524 + ks * 32 + quad * 8];
        acc[m] = MFMA16(a, vbv, acc[m]);
      }
    }
#pragma unroll
    for (int m = 0; m < 4; ++m)
#pragma unroll
      for (int r = 0; r < 4; ++r) {
        const int c = m * 16 + quad * 4 + r;
        size_t o = ((size_t)(b * 1024 + p)) * 64 + c;
        Xc[o] = f2bf(acc[m][r] * RS[c] + bf2f(QT[o]));
      }
  }
}

// ---------------- conv5 body (one stem): bid in [0,256) --------------------
__device__ __forceinline__ void conv5_body(char* ws, const float* b1p, int s, int bid)
{
  __shared__ float Hbuf[2][16][65];
  __shared__ float red[2][2];

  const int b = bid >> 5, pt = bid & 31;
  const int w = threadIdx.x >> 6, lane = threadIdx.x & 63;
  const int low4 = lane & 15, quad = lane >> 4;
  const int wsub = w & 1, half = w >> 1;

  const unsigned short* X = (const unsigned short*)(ws + (s ? O_XC : O_XS));
  const unsigned short* W1t = (const unsigned short*)(ws + O_W1T);
  unsigned short* Yt = (unsigned short*)(ws + O_YT);
  float* stats = (float*)(ws + O_STATS);

  const int p = pt * 32 + wsub * 16 + low4;
  const int y0 = p >> 5, x0 = p & 31;

  f4 acc[4];
#pragma unroll
  for (int m = 0; m < 4; ++m) acc[m] = (f4){0.f, 0.f, 0.f, 0.f};

  const int o0 = half ? 13 : 0, o1 = half ? 25 : 13;
  for (int off = o0; off < o1; ++off) {
    const int dy = off / 5 - 2, dx = off % 5 - 2;
    const int ys = y0 + dy, xs = x0 + dx;
    const bool valid = ((unsigned)ys < 32u) & ((unsigned)xs < 32u);
    const int psrc = valid ? (p + dy * 32 + dx) : p;
    const unsigned short* xp = X + ((size_t)(b * 1024 + psrc)) * 64;
    const unsigned short* wp = W1t + ((size_t)((s * 25 + off) * 64)) * 64;
#pragma unroll
    for (int ks = 0; ks < 2; ++ks) {
      short8 bv = *(const short8*)(xp + ks * 32 + quad * 8);
      if (!valid) bv = (short8)0;
#pragma unroll
      for (int m = 0; m < 4; ++m) {
        short8 av = *(const short8*)(wp + (m * 16 + low4) * 64 + ks * 32 + quad * 8);
        acc[m] = MFMA16(av, bv, acc[m]);
      }
    }
  }

  if (half) {
#pragma unroll
    for (int m = 0; m < 4; ++m)
#pragma unroll
      for (int r = 0; r < 4; ++r)
        Hbuf[wsub][low4][m * 16 + quad * 4 + r] = acc[m][r];
  }
  __syncthreads();
  if (!half) {
    float ls = 0.f, ls2 = 0.f;
#pragma unroll
    for (int m = 0; m < 4; ++m)
#pragma unroll
      for (int r = 0; r < 4; ++r) {
        const int co = m * 16 + quad * 4 + r;
        float y = acc[m][r] + Hbuf[wsub][low4][co] + b1p[co];
        Yt[((size_t)((s * 8 + b) * 1024 + p)) * 64 + co] = f2bf(y);
        ls += y; ls2 += y * y;
      }
#pragma unroll
    for (int o = 1; o < 64; o <<= 1) {
      ls += __shfl_xor(ls, o, 64);
      ls2 += __shfl_xor(ls2, o, 64);
    }
    if (lane == 0) { red[0][wsub] = ls; red[1][wsub] = ls2; }
  }
  __syncthreads();
  if (threadIdx.x == 0) {
    atomicAdd(&stats[(s * 8 + b) * 2 + 0], red[0][0] + red[0][1]);
    atomicAdd(&stats[(s * 8 + b) * 2 + 1], red[1][0] + red[1][1]);
  }
}

// ---------------- final body (one stem): bid in [0,256) --------------------
__device__ __forceinline__ void final_body(char* ws, const float* b2p,
                                           float* out, int s, int bid)
{
  const int b = bid >> 5, pt = bid & 31;
  const int w = threadIdx.x >> 6, lane = threadIdx.x & 63;
  const int low4 = lane & 15, quad = lane >> 4;
  const int p2 = pt * 32 + (w & 1) * 16 + low4;
  const int nh0 = (w >> 1) * 64;

  const unsigned short* Yt = (const unsigned short*)(ws + O_YT);
  const unsigned short* LNW = (const unsigned short*)(ws + O_LNW);
  const unsigned short* LNB = (const unsigned short*)(ws + O_LNB);
  const unsigned short* W2b = (const unsigned short*)(ws + O_W2B);
  const float* stats = (const float*)(ws + O_STATS);

  const float inv = 1.0f / 65536.0f;
  const float mu = stats[(s * 8 + b) * 2 + 0] * inv;
  const float ms = stats[(s * 8 + b) * 2 + 1] * inv;
  const float rsig = rsqrtf(ms - mu * mu + 1e-5f);

  f4 acc[4];
#pragma unroll
  for (int m = 0; m < 4; ++m) acc[m] = (f4){0.f, 0.f, 0.f, 0.f};

#pragma unroll
  for (int ks = 0; ks < 2; ++ks) {
    size_t yo = ((size_t)((s * 8 + b) * 1024 + p2)) * 64 + ks * 32 + quad * 8;
    size_t lo = ((size_t)(s * 1024 + p2)) * 64 + ks * 32 + quad * 8;
    short8 yv = *(const short8*)(Yt + yo);
    short8 lw8 = *(const short8*)(LNW + lo);
    short8 lb8 = *(const short8*)(LNB + lo);
    short8 zv;
#pragma unroll
    for (int j = 0; j < 8; ++j) {
      float z = (bf2f((unsigned short)yv[j]) - mu) * rsig * bf2f((unsigned short)lw8[j]) +
                bf2f((unsigned short)lb8[j]);
      zv[j] = (short)f2bf(fmaxf(z, 0.f));
    }
#pragma unroll
    for (int m = 0; m < 4; ++m) {
      short8 a = *(const short8*)(W2b + ((size_t)(s * 128 + nh0 + m * 16 + low4)) * 64 + ks * 32 + quad * 8);
      acc[m] = MFMA16(a, zv, acc[m]);
    }
  }
#pragma unroll
  for (int m = 0; m < 4; ++m)
#pragma unroll
    for (int r = 0; r < 4; ++r) {
      const int nh = nh0 + m * 16 + quad * 4 + r;
      out[((size_t)((s * 8 + b) * 128 + nh)) * 1024 + p2] = acc[m][r] + b2p[nh];
    }
}

// ============================================================================
// K4: both conv5 stems (512 blocks)
// ============================================================================
__global__ __launch_bounds__(256) void k4_conv(char* __restrict__ ws,
                                               const float* __restrict__ sb1,
                                               const float* __restrict__ cb1)
{
  const int s = blockIdx.x >> 8;
  conv5_body(ws, s ? cb1 : sb1, s, blockIdx.x & 255);
}

// ============================================================================
// K5: both finals (512 blocks)
// ============================================================================
__global__ __launch_bounds__(256) void k5_final(char* __restrict__ ws,
                                                const float* __restrict__ sb2,
                                                const float* __restrict__ cb2,
                                                float* __restrict__ out)
{
  const int s = blockIdx.x >> 8;
  final_body(ws, s ? cb2 : sb2, out, s, blockIdx.x & 255);
}

extern "C" void kernel_launch(void* const* d_in, const int* in_sizes, int n_in,
                              void* d_out, int out_size, void* d_ws, size_t ws_size,
                              hipStream_t stream)
{
  const float* q    = (const float*)d_in[0];
  const float* keys = (const float*)d_in[1];
  const float* vals = (const float*)d_in[2];
  const float* sw1  = (const float*)d_in[3];
  const float* sb1  = (const float*)d_in[4];
  const float* slnw = (const float*)d_in[5];
  const float* slnb = (const float*)d_in[6];
  const float* sw2  = (const float*)d_in[7];
  const float* sb2  = (const float*)d_in[8];
  const float* cw1  = (const float*)d_in[9];
  const float* cb1  = (const float*)d_in[10];
  const float* clnw = (const float*)d_in[11];
  const float* clnb = (const float*)d_in[12];
  const float* cw2  = (const float*)d_in[13];
  const float* cb2  = (const float*)d_in[14];
  char* ws = (char*)d_ws;

  (void)hipMemsetAsync(ws + O_STATS, 0, 256, stream);
  k1_prep<<<3104, 256, 0, stream>>>(q, keys, vals, sw1, slnw, slnb, sw2,
                                    cw1, clnw, clnb, cw2, ws);
  k2_spat_chanS<<<640, 256, 0, stream>>>(q, keys, ws);
  k3_finS_chanB<<<640, 256, 0, stream>>>(vals, ws);
  k4_conv<<<512, 256, 0, stream>>>(ws, sb1, cb1);
  k5_final<<<512, 256, 0, stream>>>(ws, sb2, cb2, (float*)d_out);
}